// Round 3
// baseline (235.870 us; speedup 1.0000x reference)
//
#include <hip/hip_runtime.h>

using bf16 = __bf16;
typedef __bf16 bf16x8 __attribute__((ext_vector_type(8)));
typedef __bf16 bf16x4 __attribute__((ext_vector_type(4)));
typedef float  f32x4  __attribute__((ext_vector_type(4)));

#define MFMA16(a, b, c) __builtin_amdgcn_mfma_f32_16x16x32_bf16((a), (b), (c), 0, 0, 0)

static constexpr int S = 2048, E = 1024;
static constexpr float CSCALE = 0.18033688011112042f;  // 1/sqrt(64) * log2(e)

__device__ __forceinline__ void gld16(const bf16* g, bf16* l) {
    __builtin_amdgcn_global_load_lds((const __attribute__((address_space(1))) unsigned*)g,
                                     (__attribute__((address_space(3))) unsigned*)l, 16, 0, 0);
}

// ---------------- fp32 -> bf16 elementwise ----------------
__global__ __launch_bounds__(256) void k_cvt(const float* __restrict__ in, bf16* __restrict__ out, int n) {
    int i = (blockIdx.x * 256 + threadIdx.x) * 4;
    if (i >= n) return;
    float4 v = *(const float4*)(in + i);
    bf16x4 o = { (bf16)v.x, (bf16)v.y, (bf16)v.z, (bf16)v.w };
    *(bf16x4*)(out + i) = o;
}

// ---------------- transpose+convert: in [K][N] f32 -> out [N][K] bf16 ----------------
__global__ __launch_bounds__(256) void k_tcvt(const float* __restrict__ in, bf16* __restrict__ out, int K, int N) {
    __shared__ float tile[32][33];
    int bx = blockIdx.x * 32;  // N
    int by = blockIdx.y * 32;  // K
    int tx = threadIdx.x & 31, ty = threadIdx.x >> 5;
#pragma unroll
    for (int i = 0; i < 32; i += 8)
        tile[ty + i][tx] = in[(long)(by + ty + i) * N + bx + tx];
    __syncthreads();
#pragma unroll
    for (int i = 0; i < 32; i += 8)
        out[(long)(bx + ty + i) * K + by + tx] = (bf16)tile[tx][ty + i];
}

// ---------------- bf16 GEMM (m97-style global_load_lds staging) ----------------
template <bool OUT_F32>
__global__ __launch_bounds__(256) void k_gemm_bt(const bf16* __restrict__ A, const bf16* __restrict__ Bt,
                                                 const float* __restrict__ bias, void* __restrict__ Cout,
                                                 int Mm, int Nn, int Kk, int scale_cols, float scale) {
    const int bm = blockIdx.x * 128;
    const int bn = blockIdx.y * 128;
    const int tid = threadIdx.x;
    const int w = tid >> 6, lane = tid & 63;
    const int wm = (w >> 1) * 64, wn = (w & 1) * 64;
    const int col = lane & 15, quad = lane >> 4;

    __shared__ bf16 sA[128 * 32];
    __shared__ bf16 sB[128 * 32];

    const int c0 = w * 128 + lane;
    const int r0 = c0 >> 2, s0 = c0 & 3;
    const int r1 = (c0 + 64) >> 2, s1 = (c0 + 64) & 3;
    const bf16* pA0 = A + (long)(bm + r0) * Kk + s0 * 8;
    const bf16* pA1 = A + (long)(bm + r1) * Kk + s1 * 8;
    const bf16* pB0 = Bt + (long)(bn + r0) * Kk + s0 * 8;
    const bf16* pB1 = Bt + (long)(bn + r1) * Kk + s1 * 8;
    bf16* lA0 = sA + w * 1024;
    bf16* lA1 = sA + w * 1024 + 512;
    bf16* lB0 = sB + w * 1024;
    bf16* lB1 = sB + w * 1024 + 512;

    f32x4 acc[4][4] = {};

    for (int k0 = 0; k0 < Kk; k0 += 32) {
        __syncthreads();
        gld16(pA0 + k0, lA0);
        gld16(pA1 + k0, lA1);
        gld16(pB0 + k0, lB0);
        gld16(pB1 + k0, lB1);
        __syncthreads();
        bf16x8 af[4], bfr[4];
#pragma unroll
        for (int mt = 0; mt < 4; mt++) af[mt] = *(const bf16x8*)(sA + (wm + mt * 16 + col) * 32 + quad * 8);
#pragma unroll
        for (int nt = 0; nt < 4; nt++) bfr[nt] = *(const bf16x8*)(sB + (wn + nt * 16 + col) * 32 + quad * 8);
#pragma unroll
        for (int mt = 0; mt < 4; mt++)
#pragma unroll
            for (int nt = 0; nt < 4; nt++)
                acc[mt][nt] = MFMA16(af[mt], bfr[nt], acc[mt][nt]);
    }

#pragma unroll
    for (int mt = 0; mt < 4; mt++) {
        const int gr = bm + wm + mt * 16 + quad * 4;
#pragma unroll
        for (int nt = 0; nt < 4; nt++) {
            const int gc = bn + wn + nt * 16 + col;
            const float bv = bias[gc];
            const float sc = (gc < scale_cols) ? scale : 1.0f;
#pragma unroll
            for (int r = 0; r < 4; r++) {
                float vv = (acc[mt][nt][r] + bv) * sc;
                if (OUT_F32) ((float*)Cout)[(long)(gr + r) * Nn + gc] = vv;
                else         ((bf16*)Cout)[(long)(gr + r) * Nn + gc] = (bf16)vv;
            }
        }
    }
}

// ---------------- causal flash attention, S^T formulation ----------------
// One 64-row q-tile per 256-thread block; wave w owns q-rows q0+w*16..+15.
// S^T = K Q^T so softmax reduces in-lane (+2 shfls); register-prefetch pipeline.
__global__ __launch_bounds__(256) void k_attn(const bf16* __restrict__ qkv, bf16* __restrict__ out) {
    const int qt = 31 - blockIdx.x;   // longest blocks first
    const int bh = blockIdx.y;        // 0..31
    const int b = bh >> 4, h = bh & 15;
    const int tid = threadIdx.x;
    const int w = tid >> 6, lane = tid & 63;
    const int col = lane & 15, quad = lane >> 4;
    const int q0 = qt * 64;

    __shared__ bf16 sK[64 * 72];
    __shared__ bf16 sVt[64 * 80];
    __shared__ bf16 sP[4][16 * 72];

    const long base = (long)b * S * 3072;
    const int ko = E + h * 64, vo = 2 * E + h * 64;

    // Q fragment (B-operand for S^T = K Q^T): lane holds Q[q0+w*16+col][quad*8+j]
    bf16x8 bq0, bq1;
    {
        const bf16* qp = qkv + base + (long)(q0 + w * 16 + col) * 3072 + h * 64 + quad * 8;
        bq0 = *(const bf16x8*)(qp);
        bq1 = *(const bf16x8*)(qp + 32);
    }

    // staging assignments
    const int krow = tid >> 2, kcol = (tid & 3) * 16;          // K: 64 rows x 64 cols, 32B/thread
    const int vkk = (tid & 31) * 2, vd0 = (tid >> 5) * 4;      // V: 2 rows x (4+4) d, 32B/thread
    const bf16* kgp = qkv + base + (long)krow * 3072 + ko + kcol;
    const bf16* vgp = qkv + base + (long)vkk * 3072 + vo + vd0;

    // prefetch kt=0
    bf16x8 kr0, kr1;
    ushort4 va0, vb0, va1, vb1;
    kr0 = *(const bf16x8*)(kgp);
    kr1 = *(const bf16x8*)(kgp + 8);
    va0 = *(const ushort4*)(vgp);
    vb0 = *(const ushort4*)(vgp + 3072);
    va1 = *(const ushort4*)(vgp + 32);
    vb1 = *(const ushort4*)(vgp + 3072 + 32);

    float m_ = -1e30f, l_ = 0.f;
    f32x4 o0 = {}, o1 = {}, o2 = {}, o3 = {};
    bf16* pw = sP[w];

#pragma unroll 1
    for (int kt = 0; kt <= qt; kt++) {
        __syncthreads();  // previous iteration's LDS readers done
        // write prefetched regs -> LDS
        *(bf16x8*)(sK + krow * 72 + kcol) = kr0;
        *(bf16x8*)(sK + krow * 72 + kcol + 8) = kr1;
        *(unsigned*)(sVt + (vd0 + 0) * 80 + vkk) = (unsigned)va0.x | ((unsigned)vb0.x << 16);
        *(unsigned*)(sVt + (vd0 + 1) * 80 + vkk) = (unsigned)va0.y | ((unsigned)vb0.y << 16);
        *(unsigned*)(sVt + (vd0 + 2) * 80 + vkk) = (unsigned)va0.z | ((unsigned)vb0.z << 16);
        *(unsigned*)(sVt + (vd0 + 3) * 80 + vkk) = (unsigned)va0.w | ((unsigned)vb0.w << 16);
        *(unsigned*)(sVt + (vd0 + 32) * 80 + vkk) = (unsigned)va1.x | ((unsigned)vb1.x << 16);
        *(unsigned*)(sVt + (vd0 + 33) * 80 + vkk) = (unsigned)va1.y | ((unsigned)vb1.y << 16);
        *(unsigned*)(sVt + (vd0 + 34) * 80 + vkk) = (unsigned)va1.z | ((unsigned)vb1.z << 16);
        *(unsigned*)(sVt + (vd0 + 35) * 80 + vkk) = (unsigned)va1.w | ((unsigned)vb1.w << 16);
        __syncthreads();

        // issue next tile's global loads now; they fly under this iteration's compute
        if (kt < qt) {
            const long off = (long)(kt + 1) * 64 * 3072;
            kr0 = *(const bf16x8*)(kgp + off);
            kr1 = *(const bf16x8*)(kgp + off + 8);
            va0 = *(const ushort4*)(vgp + off);
            vb0 = *(const ushort4*)(vgp + off + 3072);
            va1 = *(const ushort4*)(vgp + off + 32);
            vb1 = *(const ushort4*)(vgp + off + 3072 + 32);
        }

        // S^T = K Q^T : A = K-frags (m = k_local), B = Q (n = q_local)
        f32x4 s[4];
#pragma unroll
        for (int mt = 0; mt < 4; mt++) {
            const bf16* kp = sK + (mt * 16 + col) * 72 + quad * 8;
            f32x4 z = {};
            z = MFMA16(*(const bf16x8*)(kp), bq0, z);
            z = MFMA16(*(const bf16x8*)(kp + 32), bq1, z);
            s[mt] = z;
        }
        // causal mask on diagonal tile: k_local = mt*16+quad*4+r vs q_local = w*16+col
        if (kt == qt) {
#pragma unroll
            for (int mt = 0; mt < 4; mt++) {
                if (mt >= w) {
#pragma unroll
                    for (int r = 0; r < 4; r++)
                        if (mt * 16 + quad * 4 + r > w * 16 + col) s[mt][r] = -1e30f;
                }
            }
        }
        // online softmax: q lives on lane-col; reduce in-lane + xor16/xor32
        float cm = -1e30f;
#pragma unroll
        for (int mt = 0; mt < 4; mt++)
#pragma unroll
            for (int r = 0; r < 4; r++) cm = fmaxf(cm, s[mt][r]);
        cm = fmaxf(cm, __shfl_xor(cm, 16));
        cm = fmaxf(cm, __shfl_xor(cm, 32));
        const float mnew = fmaxf(m_, cm);
        const float alpha = __builtin_amdgcn_exp2f(m_ - mnew);
        m_ = mnew;
        float rs = 0.f;
#pragma unroll
        for (int mt = 0; mt < 4; mt++)
#pragma unroll
            for (int r = 0; r < 4; r++) {
                float pe = __builtin_amdgcn_exp2f(s[mt][r] - mnew);
                s[mt][r] = pe;
                rs += pe;
            }
        rs += __shfl_xor(rs, 16);
        rs += __shfl_xor(rs, 32);
        l_ = l_ * alpha + rs;
        // broadcast alpha from lane col==quad*4+r to o-rows
        float ar[4];
#pragma unroll
        for (int r = 0; r < 4; r++) ar[r] = __shfl(alpha, quad * 4 + r);
#pragma unroll
        for (int r = 0; r < 4; r++) { o0[r] *= ar[r]; o1[r] *= ar[r]; o2[r] *= ar[r]; o3[r] *= ar[r]; }
        // P^T (C-layout, k-contig per lane) -> pw[q][k], 4x ds_write_b64
#pragma unroll
        for (int mt = 0; mt < 4; mt++) {
            bf16x4 pk = { (bf16)s[mt][0], (bf16)s[mt][1], (bf16)s[mt][2], (bf16)s[mt][3] };
            *(bf16x4*)(pw + col * 72 + mt * 16 + quad * 4) = pk;
        }
        // O += P V : A = P[q][k] from pw, B = V^T frags
#pragma unroll
        for (int ks = 0; ks < 2; ks++) {
            bf16x8 ap = *(const bf16x8*)(pw + col * 72 + ks * 32 + quad * 8);
            const bf16* vb = sVt + col * 80 + ks * 32 + quad * 8;
            o0 = MFMA16(ap, *(const bf16x8*)(vb),           o0);
            o1 = MFMA16(ap, *(const bf16x8*)(vb + 16 * 80), o1);
            o2 = MFMA16(ap, *(const bf16x8*)(vb + 32 * 80), o2);
            o3 = MFMA16(ap, *(const bf16x8*)(vb + 48 * 80), o3);
        }
    }

    // epilogue: O /= l (broadcast l to o-rows), write bf16
    float lr[4];
#pragma unroll
    for (int r = 0; r < 4; r++) lr[r] = __shfl(l_, quad * 4 + r);
#pragma unroll
    for (int r = 0; r < 4; r++) {
        const float li = 1.f / lr[r];
        bf16* op = out + (long)(b * S + q0 + w * 16 + quad * 4 + r) * E + h * 64 + col;
        op[0]  = (bf16)(o0[r] * li);
        op[16] = (bf16)(o1[r] * li);
        op[32] = (bf16)(o2[r] * li);
        op[48] = (bf16)(o3[r] * li);
    }
}

extern "C" void kernel_launch(void* const* d_in, const int* in_sizes, int n_in,
                              void* d_out, int out_size, void* d_ws, size_t ws_size,
                              hipStream_t stream) {
    const float* hs = (const float*)d_in[0];   // [2,2048,1024]
    const float* w0 = (const float*)d_in[1];   // [1024,3072]
    const float* b0 = (const float*)d_in[2];   // [3072]
    const float* w1 = (const float*)d_in[3];   // [1024,1024]
    const float* b1 = (const float*)d_in[4];   // [1024]
    float* outp = (float*)d_out;               // [2,2048,1024] fp32

    char* ws = (char*)d_ws;
    bf16* A0   = (bf16*)(ws);                   // 8 MB
    bf16* Wt0  = (bf16*)(ws + 8388608);         // 6 MB
    bf16* Wt1  = (bf16*)(ws + 14680064);        // 2 MB
    bf16* qkv  = (bf16*)(ws + 16777216);        // 24 MB
    bf16* attn = (bf16*)(ws + 41943040);        // 8 MB

    k_cvt<<<4096, 256, 0, stream>>>(hs, A0, 4194304);
    k_tcvt<<<dim3(96, 32), 256, 0, stream>>>(w0, Wt0, 1024, 3072);
    k_tcvt<<<dim3(32, 32), 256, 0, stream>>>(w1, Wt1, 1024, 1024);
    k_gemm_bt<false><<<dim3(32, 24), 256, 0, stream>>>(A0, Wt0, b0, qkv, 4096, 3072, 1024, 1024, CSCALE);
    k_attn<<<dim3(32, 32), 256, 0, stream>>>(qkv, attn);
    k_gemm_bt<true><<<dim3(32, 8), 256, 0, stream>>>(attn, Wt1, b1, outp, 4096, 1024, 1024, 0, 1.0f);
}

// Round 4
// 203.366 us; speedup vs baseline: 1.1598x; 1.1598x over previous
//
#include <hip/hip_runtime.h>

using bf16 = __bf16;
typedef __bf16 bf16x8 __attribute__((ext_vector_type(8)));
typedef __bf16 bf16x4 __attribute__((ext_vector_type(4)));
typedef float  f32x4  __attribute__((ext_vector_type(4)));

#define MFMA16(a, b, c) __builtin_amdgcn_mfma_f32_16x16x32_bf16((a), (b), (c), 0, 0, 0)

static constexpr int S = 2048, E = 1024;
static constexpr float CSCALE = 0.18033688011112042f;  // 1/sqrt(64) * log2(e)

__device__ __forceinline__ void gld16(const bf16* g, bf16* l) {
    __builtin_amdgcn_global_load_lds((const __attribute__((address_space(1))) unsigned*)g,
                                     (__attribute__((address_space(3))) unsigned*)l, 16, 0, 0);
}

// ---------------- fp32 -> bf16 elementwise ----------------
__global__ __launch_bounds__(256) void k_cvt(const float* __restrict__ in, bf16* __restrict__ out, int n) {
    int i = (blockIdx.x * 256 + threadIdx.x) * 4;
    if (i >= n) return;
    float4 v = *(const float4*)(in + i);
    bf16x4 o = { (bf16)v.x, (bf16)v.y, (bf16)v.z, (bf16)v.w };
    *(bf16x4*)(out + i) = o;
}

// ---------------- transpose+convert: in [K][N] f32 -> out [N][K] bf16 ----------------
__global__ __launch_bounds__(256) void k_tcvt(const float* __restrict__ in, bf16* __restrict__ out, int K, int N) {
    __shared__ float tile[32][33];
    int bx = blockIdx.x * 32;  // N
    int by = blockIdx.y * 32;  // K
    int tx = threadIdx.x & 31, ty = threadIdx.x >> 5;
#pragma unroll
    for (int i = 0; i < 32; i += 8)
        tile[ty + i][tx] = in[(long)(by + ty + i) * N + bx + tx];
    __syncthreads();
#pragma unroll
    for (int i = 0; i < 32; i += 8)
        out[(long)(bx + ty + i) * K + by + tx] = (bf16)tile[tx][ty + i];
}

// ---------------- bf16 GEMM 128x128 (m97-style global_load_lds staging) ----------------
template <bool OUT_F32>
__global__ __launch_bounds__(256) void k_gemm_bt(const bf16* __restrict__ A, const bf16* __restrict__ Bt,
                                                 const float* __restrict__ bias, void* __restrict__ Cout,
                                                 int Mm, int Nn, int Kk, int scale_cols, float scale) {
    const int bm = blockIdx.x * 128;
    const int bn = blockIdx.y * 128;
    const int tid = threadIdx.x;
    const int w = tid >> 6, lane = tid & 63;
    const int wm = (w >> 1) * 64, wn = (w & 1) * 64;
    const int col = lane & 15, quad = lane >> 4;

    __shared__ bf16 sA[128 * 32];
    __shared__ bf16 sB[128 * 32];

    const int c0 = w * 128 + lane;
    const int r0 = c0 >> 2, s0 = c0 & 3;
    const int r1 = (c0 + 64) >> 2, s1 = (c0 + 64) & 3;
    const bf16* pA0 = A + (long)(bm + r0) * Kk + s0 * 8;
    const bf16* pA1 = A + (long)(bm + r1) * Kk + s1 * 8;
    const bf16* pB0 = Bt + (long)(bn + r0) * Kk + s0 * 8;
    const bf16* pB1 = Bt + (long)(bn + r1) * Kk + s1 * 8;
    bf16* lA0 = sA + w * 1024;
    bf16* lA1 = sA + w * 1024 + 512;
    bf16* lB0 = sB + w * 1024;
    bf16* lB1 = sB + w * 1024 + 512;

    f32x4 acc[4][4] = {};

    for (int k0 = 0; k0 < Kk; k0 += 32) {
        __syncthreads();
        gld16(pA0 + k0, lA0);
        gld16(pA1 + k0, lA1);
        gld16(pB0 + k0, lB0);
        gld16(pB1 + k0, lB1);
        __syncthreads();
        bf16x8 af[4], bfr[4];
#pragma unroll
        for (int mt = 0; mt < 4; mt++) af[mt] = *(const bf16x8*)(sA + (wm + mt * 16 + col) * 32 + quad * 8);
#pragma unroll
        for (int nt = 0; nt < 4; nt++) bfr[nt] = *(const bf16x8*)(sB + (wn + nt * 16 + col) * 32 + quad * 8);
#pragma unroll
        for (int mt = 0; mt < 4; mt++)
#pragma unroll
            for (int nt = 0; nt < 4; nt++)
                acc[mt][nt] = MFMA16(af[mt], bfr[nt], acc[mt][nt]);
    }

#pragma unroll
    for (int mt = 0; mt < 4; mt++) {
        const int gr = bm + wm + mt * 16 + quad * 4;
#pragma unroll
        for (int nt = 0; nt < 4; nt++) {
            const int gc = bn + wn + nt * 16 + col;
            const float bv = bias[gc];
            const float sc = (gc < scale_cols) ? scale : 1.0f;
#pragma unroll
            for (int r = 0; r < 4; r++) {
                float vv = (acc[mt][nt][r] + bv) * sc;
                if (OUT_F32) ((float*)Cout)[(long)(gr + r) * Nn + gc] = vv;
                else         ((bf16*)Cout)[(long)(gr + r) * Nn + gc] = (bf16)vv;
            }
        }
    }
}

// ---------------- bf16 GEMM 64x128 tile (for small-N proj: more blocks/CU) ----------------
__global__ __launch_bounds__(256) void k_gemm_bt64(const bf16* __restrict__ A, const bf16* __restrict__ Bt,
                                                    const float* __restrict__ bias, float* __restrict__ Cout,
                                                    int Mm, int Nn, int Kk) {
    const int bm = blockIdx.x * 64;
    const int bn = blockIdx.y * 128;
    const int tid = threadIdx.x;
    const int w = tid >> 6, lane = tid & 63;
    const int wm = (w >> 1) * 32, wn = (w & 1) * 64;
    const int col = lane & 15, quad = lane >> 4;

    __shared__ bf16 sA[64 * 32];
    __shared__ bf16 sB[128 * 32];

    const int ca = w * 64 + lane;                 // 256 A-chunks, 1/thread
    const int ra = ca >> 2, sa = ca & 3;
    const int c0 = w * 128 + lane;                // 512 B-chunks, 2/thread
    const int r0 = c0 >> 2, s0 = c0 & 3;
    const int r1 = (c0 + 64) >> 2, s1 = (c0 + 64) & 3;
    const bf16* pA0 = A + (long)(bm + ra) * Kk + sa * 8;
    const bf16* pB0 = Bt + (long)(bn + r0) * Kk + s0 * 8;
    const bf16* pB1 = Bt + (long)(bn + r1) * Kk + s1 * 8;
    bf16* lA0 = sA + w * 512;
    bf16* lB0 = sB + w * 1024;
    bf16* lB1 = sB + w * 1024 + 512;

    f32x4 acc[2][4] = {};

    for (int k0 = 0; k0 < Kk; k0 += 32) {
        __syncthreads();
        gld16(pA0 + k0, lA0);
        gld16(pB0 + k0, lB0);
        gld16(pB1 + k0, lB1);
        __syncthreads();
        bf16x8 af[2], bfr[4];
#pragma unroll
        for (int mt = 0; mt < 2; mt++) af[mt] = *(const bf16x8*)(sA + (wm + mt * 16 + col) * 32 + quad * 8);
#pragma unroll
        for (int nt = 0; nt < 4; nt++) bfr[nt] = *(const bf16x8*)(sB + (wn + nt * 16 + col) * 32 + quad * 8);
#pragma unroll
        for (int mt = 0; mt < 2; mt++)
#pragma unroll
            for (int nt = 0; nt < 4; nt++)
                acc[mt][nt] = MFMA16(af[mt], bfr[nt], acc[mt][nt]);
    }

#pragma unroll
    for (int mt = 0; mt < 2; mt++) {
        const int gr = bm + wm + mt * 16 + quad * 4;
#pragma unroll
        for (int nt = 0; nt < 4; nt++) {
            const int gc = bn + wn + nt * 16 + col;
            const float bv = bias[gc];
#pragma unroll
            for (int r = 0; r < 4; r++)
                Cout[(long)(gr + r) * Nn + gc] = acc[mt][nt][r] + bv;
        }
    }
}

// ---------------- causal flash attention: paired q-tiles, O^T, double-buffer ----------------
// Block = 4 waves, handles q-tiles (31-p) then (p): 33 iterations, uniform across all 512 blocks.
// S^T = K Q^T (softmax in-lane + 2 shfls); O^T = V^T P^T (alpha/l fully in-lane, l deferred).
__global__ __launch_bounds__(256) void k_attn(const bf16* __restrict__ qkv, bf16* __restrict__ out) {
    const int p = blockIdx.x;         // 0..15
    const int bh = blockIdx.y;        // 0..31
    const int b = bh >> 4, h = bh & 15;
    const int tid = threadIdx.x;
    const int w = tid >> 6, lane = tid & 63;
    const int col = lane & 15, quad = lane >> 4;

    __shared__ bf16 sK[2][64 * 72];
    __shared__ bf16 sVt[2][64 * 80];
    __shared__ bf16 sP[4][16 * 72];

    const long base = (long)b * S * 3072;
    const int ko = E + h * 64, vo = 2 * E + h * 64;

    const int krow = tid >> 2, kcol = (tid & 3) * 16;      // K staging: 32B/thread
    const int vkk = (tid & 31) * 2, vd0 = (tid >> 5) * 4;  // V staging: 2x16B, transposed pack
    const bf16* kgp = qkv + base + (long)krow * 3072 + ko + kcol;
    const bf16* vgp = qkv + base + (long)vkk * 3072 + vo + vd0;
    bf16* pw = sP[w];

    // prefetch kt=0
    bf16x8 kr0 = *(const bf16x8*)(kgp);
    bf16x8 kr1 = *(const bf16x8*)(kgp + 8);
    ushort4 va0 = *(const ushort4*)(vgp);
    ushort4 vb0 = *(const ushort4*)(vgp + 3072);
    ushort4 va1 = *(const ushort4*)(vgp + 32);
    ushort4 vb1 = *(const ushort4*)(vgp + 3072 + 32);

    int buf = 0;
#pragma unroll 1
    for (int sel = 0; sel < 2; sel++) {
        const int qt = sel ? p : 31 - p;
        const int q0 = qt * 64;
        bf16x8 bq0, bq1;
        {
            const bf16* qp = qkv + base + (long)(q0 + w * 16 + col) * 3072 + h * 64 + quad * 8;
            bq0 = *(const bf16x8*)(qp);
            bq1 = *(const bf16x8*)(qp + 32);
        }
        float m_ = -1e30f, l_ = 0.f;
        f32x4 o0 = {}, o1 = {}, o2 = {}, o3 = {};

#pragma unroll 1
        for (int kt = 0; kt <= qt; kt++) {
            bf16* bK = sK[buf];
            bf16* bV = sVt[buf];
            buf ^= 1;
            // stage prefetched regs -> LDS (double-buffered: single barrier per iter)
            *(bf16x8*)(bK + krow * 72 + kcol) = kr0;
            *(bf16x8*)(bK + krow * 72 + kcol + 8) = kr1;
            *(unsigned*)(bV + (vd0 + 0) * 80 + vkk) = (unsigned)va0.x | ((unsigned)vb0.x << 16);
            *(unsigned*)(bV + (vd0 + 1) * 80 + vkk) = (unsigned)va0.y | ((unsigned)vb0.y << 16);
            *(unsigned*)(bV + (vd0 + 2) * 80 + vkk) = (unsigned)va0.z | ((unsigned)vb0.z << 16);
            *(unsigned*)(bV + (vd0 + 3) * 80 + vkk) = (unsigned)va0.w | ((unsigned)vb0.w << 16);
            *(unsigned*)(bV + (vd0 + 32) * 80 + vkk) = (unsigned)va1.x | ((unsigned)vb1.x << 16);
            *(unsigned*)(bV + (vd0 + 33) * 80 + vkk) = (unsigned)va1.y | ((unsigned)vb1.y << 16);
            *(unsigned*)(bV + (vd0 + 34) * 80 + vkk) = (unsigned)va1.z | ((unsigned)vb1.z << 16);
            *(unsigned*)(bV + (vd0 + 35) * 80 + vkk) = (unsigned)va1.w | ((unsigned)vb1.w << 16);
            __syncthreads();

            // issue next tile's global prefetch (covers sel-boundary: next is kt=0)
            bool pf = true;
            long noff = 0;
            if (kt < qt) noff = (long)(kt + 1) * 64 * 3072;
            else if (sel == 1) pf = false;
            if (pf) {
                kr0 = *(const bf16x8*)(kgp + noff);
                kr1 = *(const bf16x8*)(kgp + noff + 8);
                va0 = *(const ushort4*)(vgp + noff);
                vb0 = *(const ushort4*)(vgp + noff + 3072);
                va1 = *(const ushort4*)(vgp + noff + 32);
                vb1 = *(const ushort4*)(vgp + noff + 3072 + 32);
            }

            // S^T = K Q^T
            f32x4 s[4];
#pragma unroll
            for (int mt = 0; mt < 4; mt++) {
                const bf16* kp = bK + (mt * 16 + col) * 72 + quad * 8;
                f32x4 z = {};
                z = MFMA16(*(const bf16x8*)(kp), bq0, z);
                z = MFMA16(*(const bf16x8*)(kp + 32), bq1, z);
                s[mt] = z;
            }
            if (kt == qt) {  // causal mask, diagonal tile
#pragma unroll
                for (int mt = 0; mt < 4; mt++) {
                    if (mt >= w) {
#pragma unroll
                        for (int r = 0; r < 4; r++)
                            if (mt * 16 + quad * 4 + r > w * 16 + col) s[mt][r] = -1e30f;
                    }
                }
            }
            // online softmax: only the max needs cross-lane (2 shfls); l deferred to epilogue
            float cm = -1e30f;
#pragma unroll
            for (int mt = 0; mt < 4; mt++)
#pragma unroll
                for (int r = 0; r < 4; r++) cm = fmaxf(cm, s[mt][r]);
            cm = fmaxf(cm, __shfl_xor(cm, 16));
            cm = fmaxf(cm, __shfl_xor(cm, 32));
            const float mnew = fmaxf(m_, cm);
            const float alpha = __builtin_amdgcn_exp2f(m_ - mnew);
            m_ = mnew;
            float rs = 0.f;
#pragma unroll
            for (int mt = 0; mt < 4; mt++)
#pragma unroll
                for (int r = 0; r < 4; r++) {
                    float pe = __builtin_amdgcn_exp2f(s[mt][r] - mnew);
                    s[mt][r] = pe;
                    rs += pe;
                }
            l_ = l_ * alpha + rs;      // per-lane partial; cross-lane sum at epilogue
#pragma unroll
            for (int r = 0; r < 4; r++) { o0[r] *= alpha; o1[r] *= alpha; o2[r] *= alpha; o3[r] *= alpha; }
            // P^T (k-contig per lane) -> pw[q][k]
#pragma unroll
            for (int mt = 0; mt < 4; mt++) {
                bf16x4 pk = { (bf16)s[mt][0], (bf16)s[mt][1], (bf16)s[mt][2], (bf16)s[mt][3] };
                *(bf16x4*)(pw + col * 72 + mt * 16 + quad * 4) = pk;
            }
            // O^T += V^T P^T : A-operand = V^T frag, B-operand = P^T frag (same LDS reads as PV)
#pragma unroll
            for (int ks = 0; ks < 2; ks++) {
                bf16x8 ap = *(const bf16x8*)(pw + col * 72 + ks * 32 + quad * 8);
                const bf16* vb = bV + col * 80 + ks * 32 + quad * 8;
                o0 = MFMA16(*(const bf16x8*)(vb),           ap, o0);
                o1 = MFMA16(*(const bf16x8*)(vb + 16 * 80), ap, o1);
                o2 = MFMA16(*(const bf16x8*)(vb + 32 * 80), ap, o2);
                o3 = MFMA16(*(const bf16x8*)(vb + 48 * 80), ap, o3);
            }
        }

        // epilogue: finish l reduction, O^T rows = d (contig per lane) -> b64 stores
        float lt = l_;
        lt += __shfl_xor(lt, 16);
        lt += __shfl_xor(lt, 32);
        const float li = 1.f / lt;
        bf16* op = out + (long)(b * S + q0 + w * 16 + col) * E + h * 64 + quad * 4;
        f32x4 oo[4] = { o0, o1, o2, o3 };
#pragma unroll
        for (int mt = 0; mt < 4; mt++) {
            bf16x4 ov = { (bf16)(oo[mt][0] * li), (bf16)(oo[mt][1] * li),
                          (bf16)(oo[mt][2] * li), (bf16)(oo[mt][3] * li) };
            *(bf16x4*)(op + mt * 16) = ov;
        }
    }
}

extern "C" void kernel_launch(void* const* d_in, const int* in_sizes, int n_in,
                              void* d_out, int out_size, void* d_ws, size_t ws_size,
                              hipStream_t stream) {
    const float* hs = (const float*)d_in[0];   // [2,2048,1024]
    const float* w0 = (const float*)d_in[1];   // [1024,3072]
    const float* b0 = (const float*)d_in[2];   // [3072]
    const float* w1 = (const float*)d_in[3];   // [1024,1024]
    const float* b1 = (const float*)d_in[4];   // [1024]
    float* outp = (float*)d_out;               // [2,2048,1024] fp32

    char* ws = (char*)d_ws;
    bf16* A0   = (bf16*)(ws);                   // 8 MB
    bf16* Wt0  = (bf16*)(ws + 8388608);         // 6 MB
    bf16* Wt1  = (bf16*)(ws + 14680064);        // 2 MB
    bf16* qkv  = (bf16*)(ws + 16777216);        // 24 MB
    bf16* attn = (bf16*)(ws + 41943040);        // 8 MB

    k_cvt<<<4096, 256, 0, stream>>>(hs, A0, 4194304);
    k_tcvt<<<dim3(96, 32), 256, 0, stream>>>(w0, Wt0, 1024, 3072);
    k_tcvt<<<dim3(32, 32), 256, 0, stream>>>(w1, Wt1, 1024, 1024);
    k_gemm_bt<false><<<dim3(32, 24), 256, 0, stream>>>(A0, Wt0, b0, qkv, 4096, 3072, 1024, 1024, CSCALE);
    k_attn<<<dim3(16, 32), 256, 0, stream>>>(qkv, attn);
    k_gemm_bt64<<<dim3(64, 8), 256, 0, stream>>>(attn, Wt1, b1, outp, 4096, 1024, 1024);
}

// Round 5
// 187.161 us; speedup vs baseline: 1.2602x; 1.0866x over previous
//
#include <hip/hip_runtime.h>

using bf16 = __bf16;
typedef __bf16 bf16x8 __attribute__((ext_vector_type(8)));
typedef __bf16 bf16x4 __attribute__((ext_vector_type(4)));
typedef float  f32x4  __attribute__((ext_vector_type(4)));

#define MFMA16(a, b, c) __builtin_amdgcn_mfma_f32_16x16x32_bf16((a), (b), (c), 0, 0, 0)

static constexpr int S = 2048, E = 1024;
static constexpr float CSCALE = 0.18033688011112042f;  // 1/sqrt(64) * log2(e)

__device__ __forceinline__ void gld16(const bf16* g, bf16* l) {
    __builtin_amdgcn_global_load_lds((const __attribute__((address_space(1))) unsigned*)g,
                                     (__attribute__((address_space(3))) unsigned*)l, 16, 0, 0);
}

// ---------------- fused prep: cvt(hs) + transpose-cvt(w0) + transpose-cvt(w1) ----------------
__global__ __launch_bounds__(256) void k_prep(const float* __restrict__ hs, const float* __restrict__ w0,
                                              const float* __restrict__ w1, bf16* __restrict__ A0,
                                              bf16* __restrict__ Wt0, bf16* __restrict__ Wt1) {
    __shared__ float tile[32][33];
    const int bx = blockIdx.x;
    if (bx < 4096) {  // elementwise cvt, 4 f32/thread
        int i = (bx * 256 + threadIdx.x) * 4;
        float4 v = *(const float4*)(hs + i);
        bf16x4 o = { (bf16)v.x, (bf16)v.y, (bf16)v.z, (bf16)v.w };
        *(bf16x4*)(A0 + i) = o;
        return;
    }
    const float* in;
    bf16* outp;
    int K, N, nb, kb;
    if (bx < 4096 + 3072) {
        int j = bx - 4096; in = w0; outp = Wt0; K = 1024; N = 3072; nb = j % 96; kb = j / 96;
    } else {
        int j = bx - 7168; in = w1; outp = Wt1; K = 1024; N = 1024; nb = j % 32; kb = j / 32;
    }
    const int bxx = nb * 32, byy = kb * 32;
    const int tx = threadIdx.x & 31, ty = threadIdx.x >> 5;
#pragma unroll
    for (int i = 0; i < 32; i += 8)
        tile[ty + i][tx] = in[(long)(byy + ty + i) * N + bxx + tx];
    __syncthreads();
#pragma unroll
    for (int i = 0; i < 32; i += 8)
        outp[(long)(bxx + ty + i) * K + byy + tx] = (bf16)tile[tx][ty + i];
}

// ---------------- bf16 GEMM 128x128 (m97-style global_load_lds staging) ----------------
template <bool OUT_F32>
__global__ __launch_bounds__(256) void k_gemm_bt(const bf16* __restrict__ A, const bf16* __restrict__ Bt,
                                                 const float* __restrict__ bias, void* __restrict__ Cout,
                                                 int Mm, int Nn, int Kk, int scale_cols, float scale) {
    const int bm = blockIdx.x * 128;
    const int bn = blockIdx.y * 128;
    const int tid = threadIdx.x;
    const int w = tid >> 6, lane = tid & 63;
    const int wm = (w >> 1) * 64, wn = (w & 1) * 64;
    const int col = lane & 15, quad = lane >> 4;

    __shared__ bf16 sA[128 * 32];
    __shared__ bf16 sB[128 * 32];

    const int c0 = w * 128 + lane;
    const int r0 = c0 >> 2, s0 = c0 & 3;
    const int r1 = (c0 + 64) >> 2, s1 = (c0 + 64) & 3;
    const bf16* pA0 = A + (long)(bm + r0) * Kk + s0 * 8;
    const bf16* pA1 = A + (long)(bm + r1) * Kk + s1 * 8;
    const bf16* pB0 = Bt + (long)(bn + r0) * Kk + s0 * 8;
    const bf16* pB1 = Bt + (long)(bn + r1) * Kk + s1 * 8;
    bf16* lA0 = sA + w * 1024;
    bf16* lA1 = sA + w * 1024 + 512;
    bf16* lB0 = sB + w * 1024;
    bf16* lB1 = sB + w * 1024 + 512;

    f32x4 acc[4][4] = {};

    for (int k0 = 0; k0 < Kk; k0 += 32) {
        __syncthreads();
        gld16(pA0 + k0, lA0);
        gld16(pA1 + k0, lA1);
        gld16(pB0 + k0, lB0);
        gld16(pB1 + k0, lB1);
        __syncthreads();
        bf16x8 af[4], bfr[4];
#pragma unroll
        for (int mt = 0; mt < 4; mt++) af[mt] = *(const bf16x8*)(sA + (wm + mt * 16 + col) * 32 + quad * 8);
#pragma unroll
        for (int nt = 0; nt < 4; nt++) bfr[nt] = *(const bf16x8*)(sB + (wn + nt * 16 + col) * 32 + quad * 8);
#pragma unroll
        for (int mt = 0; mt < 4; mt++)
#pragma unroll
            for (int nt = 0; nt < 4; nt++)
                acc[mt][nt] = MFMA16(af[mt], bfr[nt], acc[mt][nt]);
    }

#pragma unroll
    for (int mt = 0; mt < 4; mt++) {
        const int gr = bm + wm + mt * 16 + quad * 4;
#pragma unroll
        for (int nt = 0; nt < 4; nt++) {
            const int gc = bn + wn + nt * 16 + col;
            const float bv = bias[gc];
            const float sc = (gc < scale_cols) ? scale : 1.0f;
#pragma unroll
            for (int r = 0; r < 4; r++) {
                float vv = (acc[mt][nt][r] + bv) * sc;
                if (OUT_F32) ((float*)Cout)[(long)(gr + r) * Nn + gc] = vv;
                else         ((bf16*)Cout)[(long)(gr + r) * Nn + gc] = (bf16)vv;
            }
        }
    }
}

// ---------------- bf16 GEMM 64x128 tile (proj) ----------------
__global__ __launch_bounds__(256) void k_gemm_bt64(const bf16* __restrict__ A, const bf16* __restrict__ Bt,
                                                    const float* __restrict__ bias, float* __restrict__ Cout,
                                                    int Mm, int Nn, int Kk) {
    const int bm = blockIdx.x * 64;
    const int bn = blockIdx.y * 128;
    const int tid = threadIdx.x;
    const int w = tid >> 6, lane = tid & 63;
    const int wm = (w >> 1) * 32, wn = (w & 1) * 64;
    const int col = lane & 15, quad = lane >> 4;

    __shared__ bf16 sA[64 * 32];
    __shared__ bf16 sB[128 * 32];

    const int ca = w * 64 + lane;
    const int ra = ca >> 2, sa = ca & 3;
    const int c0 = w * 128 + lane;
    const int r0 = c0 >> 2, s0 = c0 & 3;
    const int r1 = (c0 + 64) >> 2, s1 = (c0 + 64) & 3;
    const bf16* pA0 = A + (long)(bm + ra) * Kk + sa * 8;
    const bf16* pB0 = Bt + (long)(bn + r0) * Kk + s0 * 8;
    const bf16* pB1 = Bt + (long)(bn + r1) * Kk + s1 * 8;
    bf16* lA0 = sA + w * 512;
    bf16* lB0 = sB + w * 1024;
    bf16* lB1 = sB + w * 1024 + 512;

    f32x4 acc[2][4] = {};

    for (int k0 = 0; k0 < Kk; k0 += 32) {
        __syncthreads();
        gld16(pA0 + k0, lA0);
        gld16(pB0 + k0, lB0);
        gld16(pB1 + k0, lB1);
        __syncthreads();
        bf16x8 af[2], bfr[4];
#pragma unroll
        for (int mt = 0; mt < 2; mt++) af[mt] = *(const bf16x8*)(sA + (wm + mt * 16 + col) * 32 + quad * 8);
#pragma unroll
        for (int nt = 0; nt < 4; nt++) bfr[nt] = *(const bf16x8*)(sB + (wn + nt * 16 + col) * 32 + quad * 8);
#pragma unroll
        for (int mt = 0; mt < 2; mt++)
#pragma unroll
            for (int nt = 0; nt < 4; nt++)
                acc[mt][nt] = MFMA16(af[mt], bfr[nt], acc[mt][nt]);
    }

#pragma unroll
    for (int mt = 0; mt < 2; mt++) {
        const int gr = bm + wm + mt * 16 + quad * 4;
#pragma unroll
        for (int nt = 0; nt < 4; nt++) {
            const int gc = bn + wn + nt * 16 + col;
            const float bv = bias[gc];
#pragma unroll
            for (int r = 0; r < 4; r++)
                Cout[(long)(gr + r) * Nn + gc] = acc[mt][nt][r] + bv;
        }
    }
}

// ---------------- causal flash attention: q=32/wave, 128-row q-tiles, balanced 1D grid ----------------
// Block = 4 waves, one 128-row q-tile; wave w owns q-rows w*32 + qg*16 + col (qg=0,1).
// Grid 512: L<256 -> heavy tiles (qt=15-(L>>5)), L>=256 -> light (qt=(L>>5)-8); with 2 blocks/CU
// the (i, i+256) co-residency pairs heavy+light -> ~uniform 34 iters per CU.
__global__ __launch_bounds__(256) void k_attn(const bf16* __restrict__ qkv, bf16* __restrict__ out) {
    const int L = blockIdx.x;
    const int bh = L & 31;
    const int t = L >> 5;
    const int qt = (t < 8) ? (15 - t) : (t - 8);
    const int b = bh >> 4, h = bh & 15;
    const int tid = threadIdx.x;
    const int w = tid >> 6, lane = tid & 63;
    const int col = lane & 15, quad = lane >> 4;
    const int q0 = qt * 128;
    const int nkt = 2 * qt + 2;

    __shared__ bf16 sK[2][64 * 72];
    __shared__ bf16 sVt[2][64 * 80];
    __shared__ bf16 sP[4][32 * 72];

    const long base = (long)b * S * 3072;
    const int ko = E + h * 64, vo = 2 * E + h * 64;

    // Q fragments: 2 q-groups x 2 k-halves
    bf16x8 bq[2][2];
#pragma unroll
    for (int qg = 0; qg < 2; qg++) {
        const bf16* qp = qkv + base + (long)(q0 + w * 32 + qg * 16 + col) * 3072 + h * 64 + quad * 8;
        bq[qg][0] = *(const bf16x8*)(qp);
        bq[qg][1] = *(const bf16x8*)(qp + 32);
    }

    const int krow = tid >> 2, kcol = (tid & 3) * 16;
    const int vkk = (tid & 31) * 2, vd0 = (tid >> 5) * 4;
    const bf16* kgp = qkv + base + (long)krow * 3072 + ko + kcol;
    const bf16* vgp = qkv + base + (long)vkk * 3072 + vo + vd0;
    bf16* pw = sP[w];

    // prefetch kt=0
    bf16x8 kr0 = *(const bf16x8*)(kgp);
    bf16x8 kr1 = *(const bf16x8*)(kgp + 8);
    ushort4 va0 = *(const ushort4*)(vgp);
    ushort4 vb0 = *(const ushort4*)(vgp + 3072);
    ushort4 va1 = *(const ushort4*)(vgp + 32);
    ushort4 vb1 = *(const ushort4*)(vgp + 3072 + 32);

    float m_[2] = { -1e30f, -1e30f }, l_[2] = { 0.f, 0.f };
    f32x4 o[2][4] = {};

    int buf = 0;
#pragma unroll 1
    for (int kt = 0; kt < nkt; kt++) {
        bf16* bK = sK[buf];
        bf16* bV = sVt[buf];
        buf ^= 1;
        *(bf16x8*)(bK + krow * 72 + kcol) = kr0;
        *(bf16x8*)(bK + krow * 72 + kcol + 8) = kr1;
        *(unsigned*)(bV + (vd0 + 0) * 80 + vkk) = (unsigned)va0.x | ((unsigned)vb0.x << 16);
        *(unsigned*)(bV + (vd0 + 1) * 80 + vkk) = (unsigned)va0.y | ((unsigned)vb0.y << 16);
        *(unsigned*)(bV + (vd0 + 2) * 80 + vkk) = (unsigned)va0.z | ((unsigned)vb0.z << 16);
        *(unsigned*)(bV + (vd0 + 3) * 80 + vkk) = (unsigned)va0.w | ((unsigned)vb0.w << 16);
        *(unsigned*)(bV + (vd0 + 32) * 80 + vkk) = (unsigned)va1.x | ((unsigned)vb1.x << 16);
        *(unsigned*)(bV + (vd0 + 33) * 80 + vkk) = (unsigned)va1.y | ((unsigned)vb1.y << 16);
        *(unsigned*)(bV + (vd0 + 34) * 80 + vkk) = (unsigned)va1.z | ((unsigned)vb1.z << 16);
        *(unsigned*)(bV + (vd0 + 35) * 80 + vkk) = (unsigned)va1.w | ((unsigned)vb1.w << 16);
        __syncthreads();

        if (kt + 1 < nkt) {
            const long noff = (long)(kt + 1) * 64 * 3072;
            kr0 = *(const bf16x8*)(kgp + noff);
            kr1 = *(const bf16x8*)(kgp + noff + 8);
            va0 = *(const ushort4*)(vgp + noff);
            vb0 = *(const ushort4*)(vgp + noff + 3072);
            va1 = *(const ushort4*)(vgp + noff + 32);
            vb1 = *(const ushort4*)(vgp + noff + 3072 + 32);
        }

        // S^T = K Q^T: K-frags shared across both q-groups
        f32x4 s[2][4];
#pragma unroll
        for (int mt = 0; mt < 4; mt++) {
            const bf16* kp = bK + (mt * 16 + col) * 72 + quad * 8;
            const bf16x8 ka0 = *(const bf16x8*)(kp);
            const bf16x8 ka1 = *(const bf16x8*)(kp + 32);
#pragma unroll
            for (int qg = 0; qg < 2; qg++) {
                f32x4 z = {};
                z = MFMA16(ka0, bq[qg][0], z);
                z = MFMA16(ka1, bq[qg][1], z);
                s[qg][mt] = z;
            }
        }
        if (kt >= 2 * qt) {  // diagonal region: causal mask
#pragma unroll
            for (int qg = 0; qg < 2; qg++) {
                const int qrow = q0 + w * 32 + qg * 16 + col;
#pragma unroll
                for (int mt = 0; mt < 4; mt++)
#pragma unroll
                    for (int r = 0; r < 4; r++)
                        if (kt * 64 + mt * 16 + quad * 4 + r > qrow) s[qg][mt][r] = -1e30f;
            }
        }
        // online softmax per q-group (in-lane + 2 shfls); l deferred per-lane
#pragma unroll
        for (int qg = 0; qg < 2; qg++) {
            float cm = -1e30f;
#pragma unroll
            for (int mt = 0; mt < 4; mt++)
#pragma unroll
                for (int r = 0; r < 4; r++) cm = fmaxf(cm, s[qg][mt][r]);
            cm = fmaxf(cm, __shfl_xor(cm, 16));
            cm = fmaxf(cm, __shfl_xor(cm, 32));
            const float mnew = fmaxf(m_[qg], cm);
            const float alpha = __builtin_amdgcn_exp2f(m_[qg] - mnew);
            m_[qg] = mnew;
            float rs = 0.f;
#pragma unroll
            for (int mt = 0; mt < 4; mt++)
#pragma unroll
                for (int r = 0; r < 4; r++) {
                    float pe = __builtin_amdgcn_exp2f(s[qg][mt][r] - mnew);
                    s[qg][mt][r] = pe;
                    rs += pe;
                }
            l_[qg] = l_[qg] * alpha + rs;
#pragma unroll
            for (int dt = 0; dt < 4; dt++)
#pragma unroll
                for (int r = 0; r < 4; r++) o[qg][dt][r] *= alpha;
            // P^T -> pw[q][k]
#pragma unroll
            for (int mt = 0; mt < 4; mt++) {
                bf16x4 pk = { (bf16)s[qg][mt][0], (bf16)s[qg][mt][1],
                              (bf16)s[qg][mt][2], (bf16)s[qg][mt][3] };
                *(bf16x4*)(pw + (qg * 16 + col) * 72 + mt * 16 + quad * 4) = pk;
            }
        }
        // O^T += V^T P^T: V-frags shared across both q-groups
#pragma unroll
        for (int ks = 0; ks < 2; ks++) {
            bf16x8 vf[4];
#pragma unroll
            for (int dt = 0; dt < 4; dt++)
                vf[dt] = *(const bf16x8*)(bV + (dt * 16 + col) * 80 + ks * 32 + quad * 8);
#pragma unroll
            for (int qg = 0; qg < 2; qg++) {
                bf16x8 ap = *(const bf16x8*)(pw + (qg * 16 + col) * 72 + ks * 32 + quad * 8);
#pragma unroll
                for (int dt = 0; dt < 4; dt++)
                    o[qg][dt] = MFMA16(vf[dt], ap, o[qg][dt]);
            }
        }
    }

    // epilogue
#pragma unroll
    for (int qg = 0; qg < 2; qg++) {
        float lt = l_[qg];
        lt += __shfl_xor(lt, 16);
        lt += __shfl_xor(lt, 32);
        const float li = 1.f / lt;
        bf16* op = out + (long)(b * S + q0 + w * 32 + qg * 16 + col) * E + h * 64 + quad * 4;
#pragma unroll
        for (int dt = 0; dt < 4; dt++) {
            bf16x4 ov = { (bf16)(o[qg][dt][0] * li), (bf16)(o[qg][dt][1] * li),
                          (bf16)(o[qg][dt][2] * li), (bf16)(o[qg][dt][3] * li) };
            *(bf16x4*)(op + dt * 16) = ov;
        }
    }
}

extern "C" void kernel_launch(void* const* d_in, const int* in_sizes, int n_in,
                              void* d_out, int out_size, void* d_ws, size_t ws_size,
                              hipStream_t stream) {
    const float* hs = (const float*)d_in[0];   // [2,2048,1024]
    const float* w0 = (const float*)d_in[1];   // [1024,3072]
    const float* b0 = (const float*)d_in[2];   // [3072]
    const float* w1 = (const float*)d_in[3];   // [1024,1024]
    const float* b1 = (const float*)d_in[4];   // [1024]
    float* outp = (float*)d_out;               // [2,2048,1024] fp32

    char* ws = (char*)d_ws;
    bf16* A0   = (bf16*)(ws);                   // 8 MB
    bf16* Wt0  = (bf16*)(ws + 8388608);         // 6 MB
    bf16* Wt1  = (bf16*)(ws + 14680064);        // 2 MB
    bf16* qkv  = (bf16*)(ws + 16777216);        // 24 MB
    bf16* attn = (bf16*)(ws + 41943040);        // 8 MB

    k_prep<<<8192, 256, 0, stream>>>(hs, w0, w1, A0, Wt0, Wt1);
    k_gemm_bt<false><<<dim3(32, 24), 256, 0, stream>>>(A0, Wt0, b0, qkv, 4096, 3072, 1024, 1024, CSCALE);
    k_attn<<<512, 256, 0, stream>>>(qkv, attn);
    k_gemm_bt64<<<dim3(64, 8), 256, 0, stream>>>(attn, Wt1, b1, outp, 4096, 1024, 1024);
}